// Round 3
// baseline (702.868 us; speedup 1.0000x reference)
//
#include <hip/hip_runtime.h>
#include <stdint.h>

#define KTAPS 8
#define C 32
#define RPB 128            // out-rows per bucket: 400000 = 3125 * 128 exactly
#define NB 3125            // buckets
#define NL (NB * KTAPS)    // 25000 (bucket,k) lists
#define SEGCAP 128         // per-list capacity; count ~Poisson(64), P(>128) ~ 1e-13
#define LDSS 33            // tile row stride: bank = (rl + j) % 32 -> spread
#define OMAX 8192

// ---------------------------------------------------------------------------
// init: zero the 25000 list counters + ocount (+pad).
// ---------------------------------------------------------------------------
__global__ __launch_bounds__(256) void init_kernel(
    unsigned int* __restrict__ cnt, int n4) {
  int i = blockIdx.x * 256 + threadIdx.x;
  if (i < n4) ((uint4*)cnt)[i] = make_uint4(0u, 0u, 0u, 0u);
}

// ---------------------------------------------------------------------------
// phase A: bin rules by (ro>>7, k). Entry packs (ro&127)<<21 | ri  (28 bits).
// k = blockIdx.y (block-uniform). Scattered 4B stores hit the 25K hot
// tail lines -> L2-coalesced (verified round 2: no write-amp).
// ---------------------------------------------------------------------------
__global__ __launch_bounds__(256) void bin_kernel(
    const int* __restrict__ rules_in, const int* __restrict__ rules_out,
    unsigned int* __restrict__ cnt, unsigned int* __restrict__ bins,
    uint4* __restrict__ oflow, unsigned int* __restrict__ ocount, int R) {
  const int k = blockIdx.y;
  const int r = blockIdx.x * 256 + threadIdx.x;
  if (r >= R) return;
  const unsigned int ri = (unsigned int)rules_in[(size_t)k * R + r];
  const unsigned int ro = (unsigned int)rules_out[(size_t)k * R + r];
  const unsigned int list = (ro >> 7) * (unsigned)KTAPS + (unsigned)k;
  const unsigned int idx = atomicAdd(cnt + list, 1u);
  if (idx < (unsigned)SEGCAP) {
    bins[(size_t)list * SEGCAP + idx] = ((ro & 127u) << 21) | ri;
  } else {
    unsigned int j = atomicAdd(ocount, 1u);
    if (j < (unsigned)OMAX) oflow[j] = make_uint4(ro, ri, (unsigned)k, 0u);
  }
}

// ---------------------------------------------------------------------------
// phase B: 1024 threads/block, ONE RULE PER THREAD, zero loops around the
// GEMM (straight-line, fully static indexing -> registers, no scratch).
// T = sum over k of pad64(min(cnt,128)) <= 8*128 = 1024 exactly, so a single
// shot covers the bucket. 64-granular k-segment padding keeps k wave-uniform
// (scalar-pipe W). ds_add_f32 into 128x33 tile; block owns its 128 out rows
// -> no global atomics; epilogue = one coalesced float4 store per thread.
// ---------------------------------------------------------------------------
__global__ __launch_bounds__(1024) void gemm_bucket_kernel(
    const float* __restrict__ in, const float* __restrict__ w,
    const unsigned int* __restrict__ cnt, const unsigned int* __restrict__ bins,
    const float* __restrict__ bias, float* __restrict__ out) {
  __shared__ float tile[RPB * LDSS];   // 16.9 KB
  const int b   = blockIdx.x;
  const int tid = threadIdx.x;

  // zero the tile
  for (int i = tid; i < RPB * LDSS; i += 1024) tile[i] = 0.f;

  // segment counts + 64-padded prefix (wave-uniform scalar loads)
  const unsigned int c0 = cnt[b * KTAPS + 0] > 128u ? 128u : cnt[b * KTAPS + 0];
  const unsigned int c1 = cnt[b * KTAPS + 1] > 128u ? 128u : cnt[b * KTAPS + 1];
  const unsigned int c2 = cnt[b * KTAPS + 2] > 128u ? 128u : cnt[b * KTAPS + 2];
  const unsigned int c3 = cnt[b * KTAPS + 3] > 128u ? 128u : cnt[b * KTAPS + 3];
  const unsigned int c4 = cnt[b * KTAPS + 4] > 128u ? 128u : cnt[b * KTAPS + 4];
  const unsigned int c5 = cnt[b * KTAPS + 5] > 128u ? 128u : cnt[b * KTAPS + 5];
  const unsigned int c6 = cnt[b * KTAPS + 6] > 128u ? 128u : cnt[b * KTAPS + 6];
  const unsigned int c7 = cnt[b * KTAPS + 7] > 128u ? 128u : cnt[b * KTAPS + 7];
  const unsigned int p1 = ((c0 + 63u) & ~63u);
  const unsigned int p2 = p1 + ((c1 + 63u) & ~63u);
  const unsigned int p3 = p2 + ((c2 + 63u) & ~63u);
  const unsigned int p4 = p3 + ((c3 + 63u) & ~63u);
  const unsigned int p5 = p4 + ((c4 + 63u) & ~63u);
  const unsigned int p6 = p5 + ((c5 + 63u) & ~63u);
  const unsigned int p7 = p6 + ((c6 + 63u) & ~63u);

  __syncthreads();   // tile zeroed before any ds_add

  const unsigned int f = (unsigned int)tid;
  // segment select: padding is 64-granular => k is wave-uniform
  int k; unsigned int psk, cnk;
  if      (f <  p1) { k = 0; psk = 0;  cnk = c0; }
  else if (f <  p2) { k = 1; psk = p1; cnk = c1; }
  else if (f <  p3) { k = 2; psk = p2; cnk = c2; }
  else if (f <  p4) { k = 3; psk = p3; cnk = c3; }
  else if (f <  p5) { k = 4; psk = p4; cnk = c4; }
  else if (f <  p6) { k = 5; psk = p5; cnk = c5; }
  else if (f <  p7) { k = 6; psk = p6; cnk = c6; }
  else              { k = 7; psk = p7; cnk = c7; }
  k = __builtin_amdgcn_readfirstlane(k);

  const unsigned int i = f - psk;
  if (i < cnk) {
    const unsigned int e  = bins[((size_t)b * KTAPS + k) * SEGCAP + i];
    const unsigned int ri = e & 0x1FFFFFu;
    const unsigned int rl = (e >> 21) & 127u;

    // 8 independent 16B gathers -- all in flight together
    const float4* rowp = (const float4*)(in + (size_t)ri * C);
    float4 av[8];
#pragma unroll
    for (int j = 0; j < 8; ++j) av[j] = rowp[j];

    float a[C];
#pragma unroll
    for (int j = 0; j < 8; ++j) {
      a[4 * j + 0] = av[j].x; a[4 * j + 1] = av[j].y;
      a[4 * j + 2] = av[j].z; a[4 * j + 3] = av[j].w;
    }

    const float* wk = w + k * (C * C);   // wave-uniform -> scalar pipe
    float acc[C];
#pragma unroll
    for (int co = 0; co < C; ++co) acc[co] = a[0] * wk[co];
#pragma unroll
    for (int ci = 1; ci < C; ++ci)
#pragma unroll
      for (int co = 0; co < C; ++co)
        acc[co] = fmaf(a[ci], wk[ci * C + co], acc[co]);

    float* trow = tile + rl * LDSS;
#pragma unroll
    for (int j = 0; j < C; ++j) atomicAdd(trow + j, acc[j]);  // ds_add_f32
  }

  __syncthreads();

  // epilogue: 1024 threads = 128 rows x 8 float4 -- fully coalesced
  const int row = tid >> 3, qw = tid & 7;
  const float4 bv = ((const float4*)bias)[qw];
  const float* trow = tile + row * LDSS + qw * 4;
  float4 v;
  v.x = trow[0] + bv.x;
  v.y = trow[1] + bv.y;
  v.z = trow[2] + bv.z;
  v.w = trow[3] + bv.w;
  ((float4*)(out + ((size_t)b * RPB + row) * C))[qw] = v;
}

// ---------------------------------------------------------------------------
// overflow fixup (expected 0 entries): lane=co, broadcast a-row loads.
// ---------------------------------------------------------------------------
__global__ __launch_bounds__(256) void oflow_kernel(
    const uint4* __restrict__ oflow, const unsigned int* __restrict__ ocount,
    const float* __restrict__ in, const float* __restrict__ w,
    float* __restrict__ out) {
  const int g  = threadIdx.x >> 5;
  const int co = threadIdx.x & 31;
  unsigned int n = *ocount;
  if (n > (unsigned)OMAX) n = (unsigned)OMAX;
  for (unsigned int e = g; e < n; e += 8) {
    const uint4 ent = oflow[e];      // (ro, ri, k)
    const float* ap = in + (size_t)ent.y * C;
    const float* wk = w + ent.z * (C * C);
    float acc = 0.f;
#pragma unroll
    for (int ci = 0; ci < C; ++ci) acc = fmaf(ap[ci], wk[ci * C + co], acc);
    unsafeAtomicAdd(out + (size_t)ent.x * C + co, acc);
  }
}

// ---------------------------------------------------------------------------
// fallback (workspace too small): round-1 fused atomic path.
// ---------------------------------------------------------------------------
__global__ __launch_bounds__(256) void bias_init_kernel(
    float* __restrict__ out, const float* __restrict__ bias, int n4) {
  int idx = blockIdx.x * 256 + threadIdx.x;
  if (idx >= n4) return;
  ((float4*)out)[idx] = ((const float4*)bias)[idx & 7];
}

__global__ __launch_bounds__(256) void fused_scatter_kernel(
    const float* __restrict__ in, const float* __restrict__ w,
    const int* __restrict__ rules_in, const int* __restrict__ rules_out,
    float* __restrict__ out, int R) {
  __shared__ float cbuf[256 * LDSS];
  __shared__ int   robuf[256];
  const int k = blockIdx.y, tid = threadIdx.x;
  const int r = blockIdx.x * 256 + tid;
  const int lane = tid & 63, wbase = tid & ~63;
  if (blockIdx.x * 256 + wbase >= R) return;
  const bool valid = (r < R);
  const int rc = valid ? r : (R - 1);
  const int ri = rules_in[(size_t)k * R + rc];
  const int ro = valid ? rules_out[(size_t)k * R + rc] : -1;
  robuf[tid] = ro;
  const float4* rowp = (const float4*)(in + (size_t)ri * C);
  float4 av[8];
#pragma unroll
  for (int j = 0; j < 8; ++j) av[j] = rowp[j];
  float a[C];
#pragma unroll
  for (int j = 0; j < 8; ++j) {
    a[4 * j + 0] = av[j].x; a[4 * j + 1] = av[j].y;
    a[4 * j + 2] = av[j].z; a[4 * j + 3] = av[j].w;
  }
  const float* wk = w + k * (C * C);
  float acc[C];
#pragma unroll
  for (int co = 0; co < C; ++co) acc[co] = a[0] * wk[co];
#pragma unroll
  for (int ci = 1; ci < C; ++ci)
#pragma unroll
    for (int co = 0; co < C; ++co)
      acc[co] = fmaf(a[ci], wk[ci * C + co], acc[co]);
  float* myrow = cbuf + tid * LDSS;
#pragma unroll
  for (int co = 0; co < C; ++co) myrow[co] = acc[co];
  const int co = lane & 31, half = lane >> 5;
#pragma unroll
  for (int j = 0; j < 32; ++j) {
    const int rl  = wbase + 2 * j + half;
    const int rol = robuf[rl];
    const float v = cbuf[rl * LDSS + co];
    if (rol >= 0) unsafeAtomicAdd(out + (size_t)rol * C + co, v);
  }
}

extern "C" void kernel_launch(void* const* d_in, const int* in_sizes, int n_in,
                              void* d_out, int out_size, void* d_ws, size_t ws_size,
                              hipStream_t stream) {
  const float* in_features = (const float*)d_in[0];
  const float* weight      = (const float*)d_in[1];
  const float* bias        = (const float*)d_in[2];
  const int*   rules_in    = (const int*)d_in[3];
  const int*   rules_out   = (const int*)d_in[4];

  const int R = in_sizes[3] / KTAPS;   // 200000
  float* out = (float*)d_out;

  // workspace layout
  const size_t n_cnt    = ((size_t)NL + 4 + 3) & ~(size_t)3;
  const size_t cnt_b    = n_cnt * sizeof(unsigned int);               // ~100 KB
  const size_t bins_b   = (size_t)NL * SEGCAP * sizeof(unsigned int); // 12.8 MB
  const size_t oflow_b  = (size_t)OMAX * sizeof(uint4);               // 128 KB

  if (ws_size >= cnt_b + bins_b + oflow_b) {
    unsigned int* cnt    = (unsigned int*)d_ws;
    unsigned int* ocount = cnt + NL;
    unsigned int* bins   = (unsigned int*)((char*)d_ws + cnt_b);
    uint4*        oflow  = (uint4*)((char*)d_ws + cnt_b + bins_b);

    const int n4 = (int)(n_cnt / 4);
    init_kernel<<<(n4 + 255) / 256, 256, 0, stream>>>(cnt, n4);

    dim3 gridA((R + 255) / 256, KTAPS);
    bin_kernel<<<gridA, 256, 0, stream>>>(rules_in, rules_out, cnt, bins,
                                          oflow, ocount, R);

    gemm_bucket_kernel<<<NB, 1024, 0, stream>>>(in_features, weight, cnt, bins,
                                                bias, out);

    oflow_kernel<<<1, 256, 0, stream>>>(oflow, ocount, in_features, weight, out);
  } else {
    const int n_out4 = out_size / 4;
    bias_init_kernel<<<(n_out4 + 255) / 256, 256, 0, stream>>>(out, bias, n_out4);
    dim3 grid((R + 255) / 256, KTAPS);
    fused_scatter_kernel<<<grid, 256, 0, stream>>>(in_features, weight, rules_in,
                                                   rules_out, out, R);
  }
}

// Round 5
// 660.929 us; speedup vs baseline: 1.0635x; 1.0635x over previous
//
#include <hip/hip_runtime.h>
#include <stdint.h>

#define KTAPS 8
#define C 32
#define RPB 128            // out-rows per bucket: 400000 = 3125 * 128 exactly
#define NB 3125            // buckets
#define NL (NB * KTAPS)    // 25000 (bucket,k) lists
#define SEGCAP 128         // per-list capacity; count ~Poisson(64), P(>128) ~ 1e-13
#define LDSS 33            // tile row stride: bank = (rl + j) % 32 -> spread
#define OMAX 8192

typedef float f32x4 __attribute__((ext_vector_type(4)));

// ---------------------------------------------------------------------------
// init: zero the 25000 list counters + ocount (+pad).
// ---------------------------------------------------------------------------
__global__ __launch_bounds__(256) void init_kernel(
    unsigned int* __restrict__ cnt, int n4) {
  int i = blockIdx.x * 256 + threadIdx.x;
  if (i < n4) ((uint4*)cnt)[i] = make_uint4(0u, 0u, 0u, 0u);
}

// ---------------------------------------------------------------------------
// phase A: bin rules by (ro>>7, k). Entry packs (ro&127)<<21 | ri  (28 bits).
// k = blockIdx.y (block-uniform). Verified rounds 2/3: tail-line stores
// coalesce in L2, no write-amp; WRITE stays at the 50 MB ideal.
// ---------------------------------------------------------------------------
__global__ __launch_bounds__(256) void bin_kernel(
    const int* __restrict__ rules_in, const int* __restrict__ rules_out,
    unsigned int* __restrict__ cnt, unsigned int* __restrict__ bins,
    uint4* __restrict__ oflow, unsigned int* __restrict__ ocount, int R) {
  const int k = blockIdx.y;
  const int r = blockIdx.x * 256 + threadIdx.x;
  if (r >= R) return;
  const unsigned int ri = (unsigned int)rules_in[(size_t)k * R + r];
  const unsigned int ro = (unsigned int)rules_out[(size_t)k * R + r];
  const unsigned int list = (ro >> 7) * (unsigned)KTAPS + (unsigned)k;
  const unsigned int idx = atomicAdd(cnt + list, 1u);
  if (idx < (unsigned)SEGCAP) {
    bins[(size_t)list * SEGCAP + idx] = ((ro & 127u) << 21) | ri;
  } else {
    unsigned int j = atomicAdd(ocount, 1u);
    if (j < (unsigned)OMAX) oflow[j] = make_uint4(ro, ri, (unsigned)k, 0u);
  }
}

// ---------------------------------------------------------------------------
// phase B: 1024 threads/block, ONE RULE PER THREAD, straight-line GEMM.
// Round-3 theory (untested due to infra failure): the ds_add side-effects
// anchor a legal low-VGPR reschedule (VGPR=32: serialized gathers + 32
// dependent-chain sinks into the atomics). Empty volatile-asm fences pin the
// proven round-1 schedule:
//   fences A (2 x 4 operands): all 8 gathers issued & resolved before any
//     use -> 8-deep memory-level parallelism restored
//   fences B (2 x 4 operands): all 32 accumulator values live before the
//     first ds_add -> 32 independent fma chains, atomics issued as a block
// ---------------------------------------------------------------------------
__global__ __launch_bounds__(1024) void gemm_bucket_kernel(
    const float* __restrict__ in, const float* __restrict__ w,
    const unsigned int* __restrict__ cnt, const unsigned int* __restrict__ bins,
    const float* __restrict__ bias, float* __restrict__ out) {
  __shared__ float tile[RPB * LDSS];   // 16.9 KB
  const int b   = blockIdx.x;
  const int tid = threadIdx.x;

  // zero the tile
  for (int i = tid; i < RPB * LDSS; i += 1024) tile[i] = 0.f;

  // segment counts + 64-padded prefix (wave-uniform scalar loads)
  const unsigned int c0 = cnt[b * KTAPS + 0] > 128u ? 128u : cnt[b * KTAPS + 0];
  const unsigned int c1 = cnt[b * KTAPS + 1] > 128u ? 128u : cnt[b * KTAPS + 1];
  const unsigned int c2 = cnt[b * KTAPS + 2] > 128u ? 128u : cnt[b * KTAPS + 2];
  const unsigned int c3 = cnt[b * KTAPS + 3] > 128u ? 128u : cnt[b * KTAPS + 3];
  const unsigned int c4 = cnt[b * KTAPS + 4] > 128u ? 128u : cnt[b * KTAPS + 4];
  const unsigned int c5 = cnt[b * KTAPS + 5] > 128u ? 128u : cnt[b * KTAPS + 5];
  const unsigned int c6 = cnt[b * KTAPS + 6] > 128u ? 128u : cnt[b * KTAPS + 6];
  const unsigned int c7 = cnt[b * KTAPS + 7] > 128u ? 128u : cnt[b * KTAPS + 7];
  const unsigned int p1 = ((c0 + 63u) & ~63u);
  const unsigned int p2 = p1 + ((c1 + 63u) & ~63u);
  const unsigned int p3 = p2 + ((c2 + 63u) & ~63u);
  const unsigned int p4 = p3 + ((c3 + 63u) & ~63u);
  const unsigned int p5 = p4 + ((c4 + 63u) & ~63u);
  const unsigned int p6 = p5 + ((c5 + 63u) & ~63u);
  const unsigned int p7 = p6 + ((c6 + 63u) & ~63u);

  __syncthreads();   // tile zeroed before any ds_add

  const unsigned int f = (unsigned int)tid;
  // segment select: padding is 64-granular => k is wave-uniform
  int k; unsigned int psk, cnk;
  if      (f <  p1) { k = 0; psk = 0;  cnk = c0; }
  else if (f <  p2) { k = 1; psk = p1; cnk = c1; }
  else if (f <  p3) { k = 2; psk = p2; cnk = c2; }
  else if (f <  p4) { k = 3; psk = p3; cnk = c3; }
  else if (f <  p5) { k = 4; psk = p4; cnk = c4; }
  else if (f <  p6) { k = 5; psk = p5; cnk = c5; }
  else if (f <  p7) { k = 6; psk = p6; cnk = c6; }
  else              { k = 7; psk = p7; cnk = c7; }
  k = __builtin_amdgcn_readfirstlane(k);

  const unsigned int i = f - psk;
  if (i < cnk) {
    const unsigned int e  = bins[((size_t)b * KTAPS + k) * SEGCAP + i];
    const unsigned int ri = e & 0x1FFFFFu;
    const unsigned int rl = (e >> 21) & 127u;

    // 8 independent 16B gathers -- fences force all 8 issued & live together
    const f32x4* rowp = (const f32x4*)(in + (size_t)ri * C);
    f32x4 av[8];
#pragma unroll
    for (int j = 0; j < 8; ++j) av[j] = rowp[j];
    asm volatile("" : "+v"(av[0]), "+v"(av[1]), "+v"(av[2]), "+v"(av[3]));
    asm volatile("" : "+v"(av[4]), "+v"(av[5]), "+v"(av[6]), "+v"(av[7]));

    float a[C];
#pragma unroll
    for (int j = 0; j < 8; ++j) {
      a[4 * j + 0] = av[j].x; a[4 * j + 1] = av[j].y;
      a[4 * j + 2] = av[j].z; a[4 * j + 3] = av[j].w;
    }

    const float* wk = w + k * (C * C);   // wave-uniform -> scalar pipe
    f32x4 acc4[8];
#pragma unroll
    for (int j = 0; j < 8; ++j) {
      acc4[j].x = a[0] * wk[4 * j + 0];
      acc4[j].y = a[0] * wk[4 * j + 1];
      acc4[j].z = a[0] * wk[4 * j + 2];
      acc4[j].w = a[0] * wk[4 * j + 3];
    }
#pragma unroll
    for (int ci = 1; ci < C; ++ci)
#pragma unroll
      for (int j = 0; j < 8; ++j) {
        acc4[j].x = fmaf(a[ci], wk[ci * C + 4 * j + 0], acc4[j].x);
        acc4[j].y = fmaf(a[ci], wk[ci * C + 4 * j + 1], acc4[j].y);
        acc4[j].z = fmaf(a[ci], wk[ci * C + 4 * j + 2], acc4[j].z);
        acc4[j].w = fmaf(a[ci], wk[ci * C + 4 * j + 3], acc4[j].w);
      }
    // fences B: all 32 acc values live before the first atomic -> no sink
    asm volatile("" : "+v"(acc4[0]), "+v"(acc4[1]), "+v"(acc4[2]), "+v"(acc4[3]));
    asm volatile("" : "+v"(acc4[4]), "+v"(acc4[5]), "+v"(acc4[6]), "+v"(acc4[7]));

    float* trow = tile + rl * LDSS;
#pragma unroll
    for (int j = 0; j < 8; ++j) {
      atomicAdd(trow + 4 * j + 0, acc4[j].x);   // ds_add_f32
      atomicAdd(trow + 4 * j + 1, acc4[j].y);
      atomicAdd(trow + 4 * j + 2, acc4[j].z);
      atomicAdd(trow + 4 * j + 3, acc4[j].w);
    }
  }

  __syncthreads();

  // epilogue: 1024 threads = 128 rows x 8 float4 -- fully coalesced
  const int row = tid >> 3, qw = tid & 7;
  const float4 bv = ((const float4*)bias)[qw];
  const float* trow = tile + row * LDSS + qw * 4;
  float4 v;
  v.x = trow[0] + bv.x;
  v.y = trow[1] + bv.y;
  v.z = trow[2] + bv.z;
  v.w = trow[3] + bv.w;
  ((float4*)(out + ((size_t)b * RPB + row) * C))[qw] = v;
}

// ---------------------------------------------------------------------------
// overflow fixup (expected 0 entries): lane=co, broadcast a-row loads.
// ---------------------------------------------------------------------------
__global__ __launch_bounds__(256) void oflow_kernel(
    const uint4* __restrict__ oflow, const unsigned int* __restrict__ ocount,
    const float* __restrict__ in, const float* __restrict__ w,
    float* __restrict__ out) {
  const int g  = threadIdx.x >> 5;
  const int co = threadIdx.x & 31;
  unsigned int n = *ocount;
  if (n > (unsigned)OMAX) n = (unsigned)OMAX;
  for (unsigned int e = g; e < n; e += 8) {
    const uint4 ent = oflow[e];      // (ro, ri, k)
    const float* ap = in + (size_t)ent.y * C;
    const float* wk = w + ent.z * (C * C);
    float acc = 0.f;
#pragma unroll
    for (int ci = 0; ci < C; ++ci) acc = fmaf(ap[ci], wk[ci * C + co], acc);
    unsafeAtomicAdd(out + (size_t)ent.x * C + co, acc);
  }
}

// ---------------------------------------------------------------------------
// fallback (workspace too small): round-1 fused atomic path.
// ---------------------------------------------------------------------------
__global__ __launch_bounds__(256) void bias_init_kernel(
    float* __restrict__ out, const float* __restrict__ bias, int n4) {
  int idx = blockIdx.x * 256 + threadIdx.x;
  if (idx >= n4) return;
  ((float4*)out)[idx] = ((const float4*)bias)[idx & 7];
}

__global__ __launch_bounds__(256) void fused_scatter_kernel(
    const float* __restrict__ in, const float* __restrict__ w,
    const int* __restrict__ rules_in, const int* __restrict__ rules_out,
    float* __restrict__ out, int R) {
  __shared__ float cbuf[256 * LDSS];
  __shared__ int   robuf[256];
  const int k = blockIdx.y, tid = threadIdx.x;
  const int r = blockIdx.x * 256 + tid;
  const int lane = tid & 63, wbase = tid & ~63;
  if (blockIdx.x * 256 + wbase >= R) return;
  const bool valid = (r < R);
  const int rc = valid ? r : (R - 1);
  const int ri = rules_in[(size_t)k * R + rc];
  const int ro = valid ? rules_out[(size_t)k * R + rc] : -1;
  robuf[tid] = ro;
  const float4* rowp = (const float4*)(in + (size_t)ri * C);
  float4 av[8];
#pragma unroll
  for (int j = 0; j < 8; ++j) av[j] = rowp[j];
  float a[C];
#pragma unroll
  for (int j = 0; j < 8; ++j) {
    a[4 * j + 0] = av[j].x; a[4 * j + 1] = av[j].y;
    a[4 * j + 2] = av[j].z; a[4 * j + 3] = av[j].w;
  }
  const float* wk = w + k * (C * C);
  float acc[C];
#pragma unroll
  for (int co = 0; co < C; ++co) acc[co] = a[0] * wk[co];
#pragma unroll
  for (int ci = 1; ci < C; ++ci)
#pragma unroll
    for (int co = 0; co < C; ++co)
      acc[co] = fmaf(a[ci], wk[ci * C + co], acc[co]);
  float* myrow = cbuf + tid * LDSS;
#pragma unroll
  for (int co = 0; co < C; ++co) myrow[co] = acc[co];
  const int co = lane & 31, half = lane >> 5;
#pragma unroll
  for (int j = 0; j < 32; ++j) {
    const int rl  = wbase + 2 * j + half;
    const int rol = robuf[rl];
    const float v = cbuf[rl * LDSS + co];
    if (rol >= 0) unsafeAtomicAdd(out + (size_t)rol * C + co, v);
  }
}

extern "C" void kernel_launch(void* const* d_in, const int* in_sizes, int n_in,
                              void* d_out, int out_size, void* d_ws, size_t ws_size,
                              hipStream_t stream) {
  const float* in_features = (const float*)d_in[0];
  const float* weight      = (const float*)d_in[1];
  const float* bias        = (const float*)d_in[2];
  const int*   rules_in    = (const int*)d_in[3];
  const int*   rules_out   = (const int*)d_in[4];

  const int R = in_sizes[3] / KTAPS;   // 200000
  float* out = (float*)d_out;

  // workspace layout
  const size_t n_cnt    = ((size_t)NL + 4 + 3) & ~(size_t)3;
  const size_t cnt_b    = n_cnt * sizeof(unsigned int);               // ~100 KB
  const size_t bins_b   = (size_t)NL * SEGCAP * sizeof(unsigned int); // 12.8 MB
  const size_t oflow_b  = (size_t)OMAX * sizeof(uint4);               // 128 KB

  if (ws_size >= cnt_b + bins_b + oflow_b) {
    unsigned int* cnt    = (unsigned int*)d_ws;
    unsigned int* ocount = cnt + NL;
    unsigned int* bins   = (unsigned int*)((char*)d_ws + cnt_b);
    uint4*        oflow  = (uint4*)((char*)d_ws + cnt_b + bins_b);

    const int n4 = (int)(n_cnt / 4);
    init_kernel<<<(n4 + 255) / 256, 256, 0, stream>>>(cnt, n4);

    dim3 gridA((R + 255) / 256, KTAPS);
    bin_kernel<<<gridA, 256, 0, stream>>>(rules_in, rules_out, cnt, bins,
                                          oflow, ocount, R);

    gemm_bucket_kernel<<<NB, 1024, 0, stream>>>(in_features, weight, cnt, bins,
                                                bias, out);

    oflow_kernel<<<1, 256, 0, stream>>>(oflow, ocount, in_features, weight, out);
  } else {
    const int n_out4 = out_size / 4;
    bias_init_kernel<<<(n_out4 + 255) / 256, 256, 0, stream>>>(out, bias, n_out4);
    dim3 grid((R + 255) / 256, KTAPS);
    fused_scatter_kernel<<<grid, 256, 0, stream>>>(in_features, weight, rules_in,
                                                   rules_out, out, R);
  }
}